// Round 13
// baseline (217.549 us; speedup 1.0000x reference)
//
#include <hip/hip_runtime.h>
#include <math.h>

#define BB 4
#define HH 56
#define WW 56
#define CC 256
#define NN 3136            // HH*WW
#define SS 3137            // 1 + NN
#define NH 8
#define HD 32
#define M_ROWS (BB * SS)   // 12548
#define SPAD 3200          // padded S for vt rows (63 pad keys)
#define QSCALE (0.17677669529663687f * 1.4426950408889634f)  // 1/sqrt(32) * log2(e)
#define KT 128             // attention key-tile

typedef short short8 __attribute__((ext_vector_type(8)));   // 8 bf16 (4 VGPRs)
typedef short bf4    __attribute__((ext_vector_type(4)));   // 4 bf16 (2 VGPRs)
typedef float f32x4  __attribute__((ext_vector_type(4)));   // MFMA C/D

static __device__ __forceinline__ unsigned short f2bf(float f) {
    union { float f; unsigned u; } a; a.f = f;
    unsigned r = a.u + 0x7FFF + ((a.u >> 16) & 1);   // RNE
    return (unsigned short)(r >> 16);
}
static __device__ __forceinline__ float bf2f(unsigned short h) {
    union { unsigned u; float f; } a; a.u = ((unsigned)h) << 16; return a.f;
}

// ---------------------------------------------------------------------------
// Kernel 0: pre — small elementwise prep:
//   [0, 192)   wb = bf16(qkv_w), 4 rows/block
//   [+64)      pwhi/pwlo = bf16 split of proj_w
//   [+25)      wt[t][c] = lepe_w[c][t]  (transpose for coalesced staging)
//   [+4)       per-batch cls row: xb = bf16(cls), lepe = 0
// (vt pad zeroing removed: qkv's epilogue now writes zeros there — A-rows
//  >= SS stage as 0 so their accumulators are exactly 0.)
// ---------------------------------------------------------------------------
__global__ __launch_bounds__(256)
void pre(const float* __restrict__ cls, const float* __restrict__ qkv_w,
         const float* __restrict__ proj_w, const float* __restrict__ lepe_w,
         unsigned short* __restrict__ xb, unsigned short* __restrict__ wb,
         unsigned short* __restrict__ pwhi, unsigned short* __restrict__ pwlo,
         float* __restrict__ wt, unsigned short* __restrict__ lepe)
{
    const int B0 = 192;             // wb
    const int B1 = B0 + 64;         // pw
    const int B2 = B1 + 25;         // wt transpose
    int blk = blockIdx.x, tid = threadIdx.x;
    if (blk < B0) {
        int row = blk * 4 + (tid >> 6);          // < 768
        int c0 = (tid & 63) * 4;
        float4 v = *(const float4*)(qkv_w + (size_t)row * CC + c0);
        bf4 pk;
        pk[0] = (short)f2bf(v.x); pk[1] = (short)f2bf(v.y);
        pk[2] = (short)f2bf(v.z); pk[3] = (short)f2bf(v.w);
        *(bf4*)(wb + (size_t)row * CC + c0) = pk;
    } else if (blk < B1) {
        int row = (blk - B0) * 4 + (tid >> 6);   // < 256
        int c0 = (tid & 63) * 4;
        float4 v = *(const float4*)(proj_w + (size_t)row * CC + c0);
        bf4 ph, pl;
        float vv[4] = {v.x, v.y, v.z, v.w};
        #pragma unroll
        for (int e = 0; e < 4; ++e) {
            unsigned short h = f2bf(vv[e]);
            ph[e] = (short)h;
            pl[e] = (short)f2bf(vv[e] - bf2f(h));
        }
        *(bf4*)(pwhi + (size_t)row * CC + c0) = ph;
        *(bf4*)(pwlo + (size_t)row * CC + c0) = pl;
    } else if (blk < B2) {
        int t = blk - B1;                        // 0..24
        wt[(size_t)t * CC + tid] = lepe_w[(size_t)tid * 25 + t];
    } else {
        int b = blk - B2;                        // 0..3
        xb[((size_t)b * SS) * CC + tid] = f2bf(cls[(size_t)b * CC + tid]);
        lepe[((size_t)b * SS) * CC + tid] = 0;   // cls row: no conv term
    }
}

// ---------------------------------------------------------------------------
// Kernel 1: LDS-tiled LePE depthwise 5x5 conv + bias -> bf16 lepe, AND
// xb = bf16(x) emitted from the staged LDS tile.
// ---------------------------------------------------------------------------
__global__ __launch_bounds__(256)
void lepe_tiled(const float* __restrict__ x,
                const float* __restrict__ wt, const float* __restrict__ bias,
                unsigned short* __restrict__ lepe, unsigned short* __restrict__ xb)
{
    __shared__ unsigned short Xs[144][72];   // 12x12 halo x 64c (+8 pad)
    __shared__ float Wls[25][68];            // tap x 64c (+4 pad)

    const int tid = threadIdx.x;
    const int bid = blockIdx.x;
    const int sp  = bid % 49;
    const int ct  = (bid / 49) & 3;
    const int b   = bid / 196;
    const int y0 = (sp / 7) * 8, x0 = (sp % 7) * 8;
    const int c0 = ct * 64;

    const int cq = tid & 15;                 // c-quad within 64
    const int pg = tid >> 4;                 // 0..15

    #pragma unroll
    for (int r = 0; r < 9; ++r) {
        int seg = r * 16 + pg;               // 0..143
        int dy = seg / 12, dx = seg % 12;
        int yy = y0 + dy - 2, xc = x0 + dx - 2;
        bf4 v = {};
        if (yy >= 0 && yy < HH && xc >= 0 && xc < WW) {
            float4 f = *(const float4*)(x + (((size_t)b * HH + yy) * WW + xc) * CC
                                        + c0 + cq * 4);
            v[0] = (short)f2bf(f.x); v[1] = (short)f2bf(f.y);
            v[2] = (short)f2bf(f.z); v[3] = (short)f2bf(f.w);
        }
        *(bf4*)&Xs[seg][cq * 4] = v;
    }
    for (int idx = tid; idx < 1600; idx += 256) {
        int t = idx >> 6, c = idx & 63;
        Wls[t][c] = wt[(size_t)t * CC + c0 + c];
    }
    __syncthreads();

    float4 bq = *(const float4*)(bias + c0 + cq * 4);
    f32x4 acc[4];
    #pragma unroll
    for (int it = 0; it < 4; ++it) {
        acc[it][0] = bq.x; acc[it][1] = bq.y; acc[it][2] = bq.z; acc[it][3] = bq.w;
    }
    int hbase[4];
    #pragma unroll
    for (int it = 0; it < 4; ++it) {
        int pos = it * 16 + pg;              // 0..63
        hbase[it] = (pos >> 3) * 12 + (pos & 7);
    }

    // emit xb for this tile's 64 interior positions
    #pragma unroll
    for (int it = 0; it < 4; ++it) {
        int pos = it * 16 + pg;
        int py = pos >> 3, px = pos & 7;
        uint2 dv = *(const uint2*)&Xs[(py + 2) * 12 + (px + 2)][cq * 4];
        *(uint2*)(xb + ((size_t)(b * SS + 1 + (y0 + py) * WW + (x0 + px))) * CC
                  + c0 + cq * 4) = dv;
    }

    #pragma unroll
    for (int t = 0; t < 25; ++t) {
        int dy = t / 5, dx = t % 5;
        float4 wq = *(const float4*)&Wls[t][cq * 4];
        #pragma unroll
        for (int it = 0; it < 4; ++it) {
            const unsigned short* xp = &Xs[hbase[it] + dy * 12 + dx][cq * 4];
            uint2 dv = *(const uint2*)xp;    // 4 bf16, ds_read_b64
            float e0 = __uint_as_float(dv.x << 16);
            float e1 = __uint_as_float(dv.x & 0xFFFF0000u);
            float e2 = __uint_as_float(dv.y << 16);
            float e3 = __uint_as_float(dv.y & 0xFFFF0000u);
            acc[it][0] += e0 * wq.x; acc[it][1] += e1 * wq.y;
            acc[it][2] += e2 * wq.z; acc[it][3] += e3 * wq.w;
        }
    }

    #pragma unroll
    for (int it = 0; it < 4; ++it) {
        int pos = it * 16 + pg;
        int py = pos >> 3, px = pos & 7;
        bf4 pk;
        pk[0] = (short)f2bf(acc[it][0]); pk[1] = (short)f2bf(acc[it][1]);
        pk[2] = (short)f2bf(acc[it][2]); pk[3] = (short)f2bf(acc[it][3]);
        *(bf4*)(lepe + ((size_t)(b * SS + 1 + (y0 + py) * WW + (x0 + px))) * CC
                + c0 + cq * 4) = pk;
    }
}

// ---------------------------------------------------------------------------
// Kernel 2: qkv bf16 MFMA GEMM: [12548x256] @ [768x256]^T
// 64x128 tiles, grid (200,6), software-pipelined staging.
// Epilogue: qb (QSCALE folded), kb row-major; V^T via LDS TRANSPOSE then
// coalesced 16-B stores (old path: scattered 8-B stores with row stride
// 6400 B -> ~8x write amplification). A-rows >= SS have acc==0, so the
// boundary s-tile writes the vt pad zeros (pre's pad pass removed).
// ---------------------------------------------------------------------------
__global__ __launch_bounds__(256)
void qkv_mfma(const unsigned short* __restrict__ xb,
              const unsigned short* __restrict__ wb,
              unsigned short* __restrict__ qb, unsigned short* __restrict__ kb,
              unsigned short* __restrict__ vt)
{
    __shared__ unsigned short smem[64 * 76 + 128 * 76];   // As | Bs (29.2 KB)
    unsigned short (*As)[76] = (unsigned short (*)[76])smem;
    unsigned short (*Bs)[76] = (unsigned short (*)[76])(smem + 64 * 76);
    const int tid = threadIdx.x;
    const int w = tid >> 6, lane = tid & 63, lo = lane & 15, hi = lane >> 4;
    const int b0 = blockIdx.x / 50;
    const int s0blk = (blockIdx.x % 50) * 64;
    const int col0 = blockIdx.y * 128;
    const int wm = (w & 1) * 32, wn = (w >> 1) * 64;

    f32x4 acc[2][4] = {};

    const int arow = tid >> 3, ac8 = (tid & 7) * 8;
    const int brow = tid >> 3, bc8 = (tid & 7) * 8;

    short8 avr[2], bvr[4];
    #pragma unroll
    for (int i = 0; i < 2; ++i) {
        int row = arow + i * 32;
        short8 av = {};
        if (s0blk + row < SS)
            av = *(const short8*)(xb + (size_t)(b0 * SS + s0blk + row) * CC + ac8);
        avr[i] = av;
    }
    #pragma unroll
    for (int i = 0; i < 4; ++i)
        bvr[i] = *(const short8*)(wb + (size_t)(col0 + brow + i * 32) * CC + bc8);

    for (int k0 = 0; k0 < CC; k0 += 64) {
        __syncthreads();
        #pragma unroll
        for (int i = 0; i < 2; ++i)
            *(short8*)&As[arow + i * 32][ac8] = avr[i];
        #pragma unroll
        for (int i = 0; i < 4; ++i)
            *(short8*)&Bs[brow + i * 32][bc8] = bvr[i];
        __syncthreads();

        int kn = k0 + 64;
        if (kn < CC) {
            #pragma unroll
            for (int i = 0; i < 2; ++i) {
                int row = arow + i * 32;
                short8 av = {};
                if (s0blk + row < SS)
                    av = *(const short8*)(xb + (size_t)(b0 * SS + s0blk + row) * CC + kn + ac8);
                avr[i] = av;
            }
            #pragma unroll
            for (int i = 0; i < 4; ++i)
                bvr[i] = *(const short8*)(wb + (size_t)(col0 + brow + i * 32) * CC + kn + bc8);
        }

        #pragma unroll
        for (int kk = 0; kk < 64; kk += 32) {
            short8 af[2], bf_[4];
            #pragma unroll
            for (int m = 0; m < 2; ++m)
                af[m] = *(const short8*)&As[wm + m * 16 + lo][kk + hi * 8];
            #pragma unroll
            for (int n = 0; n < 4; ++n)
                bf_[n] = *(const short8*)&Bs[wn + n * 16 + lo][kk + hi * 8];
            #pragma unroll
            for (int m = 0; m < 2; ++m)
                #pragma unroll
                for (int n = 0; n < 4; ++n)
                    acc[m][n] = __builtin_amdgcn_mfma_f32_16x16x32_bf16(
                                    af[m], bf_[n], acc[m][n], 0, 0, 0);
        }
    }

    const int part = col0 >> 8;   // 0=q, 1=k, 2=v (block-uniform)
    if (part < 2) {
        #pragma unroll
        for (int m = 0; m < 2; ++m) {
            #pragma unroll
            for (int rr = 0; rr < 4; ++rr) {
                int s = s0blk + wm + m * 16 + hi * 4 + rr;
                if (s >= SS) continue;
                size_t r = (size_t)(b0 * SS + s);
                #pragma unroll
                for (int n = 0; n < 4; ++n) {
                    int cc = (col0 + wn + n * 16 + lo) & 255;
                    float val = acc[m][n][rr];
                    if (part == 0) qb[r * CC + cc] = f2bf(val * QSCALE);
                    else           kb[r * CC + cc] = f2bf(val);
                }
            }
        }
    } else {
        // V^T: transpose 128 cols x 64 s through LDS, then coalesced stores.
        __syncthreads();   // As/Bs reads done; reuse smem
        unsigned short (*Vst)[72] = (unsigned short (*)[72])smem;  // 128x72
        #pragma unroll
        for (int m = 0; m < 2; ++m) {
            int sl = wm + m * 16 + hi * 4;       // s_local, multiple of 4
            #pragma unroll
            for (int n = 0; n < 4; ++n) {
                int cl = wn + n * 16 + lo;       // col_local 0..127
                bf4 pk;
                pk[0] = (short)f2bf(acc[m][n][0]);
                pk[1] = (short)f2bf(acc[m][n][1]);
                pk[2] = (short)f2bf(acc[m][n][2]);
                pk[3] = (short)f2bf(acc[m][n][3]);
                *(bf4*)&Vst[cl][sl] = pk;        // 8-B aligned (72*2=144, sl%4==0)
            }
        }
        __syncthreads();
        const int cbase = col0 & 255;            // 0 or 128
        #pragma unroll
        for (int i = 0; i < 4; ++i) {
            int chunk = tid + i * 256;           // 0..1023
            int row = chunk >> 3;                // col_local 0..127
            int seg = chunk & 7;                 // 8 shorts each
            short8 v = *(const short8*)&Vst[row][seg * 8];
            int hh = (cbase + row) >> 5;
            int d  = row & 31;
            *(short8*)(vt + (size_t)((b0 * NH + hh) * HD + d) * SPAD
                       + s0blk + seg * 8) = v;   // 16-B contiguous, coalesced
        }
    }
}

// ---------------------------------------------------------------------------
// Kernel 3: bf16 MFMA flash attention, transposed-S, ones-MFMA denominator,
// software-pipelined staging, 32 q/wave. UNCHANGED (structurally pinned:
// occupancy/LDS-traffic/imbalance levers all measured neutral at 92-93 us).
// ---------------------------------------------------------------------------
__global__ __launch_bounds__(256)
void attn_mfma(const unsigned short* __restrict__ qb,
               const unsigned short* __restrict__ kb,
               const unsigned short* __restrict__ vt,
               const unsigned short* __restrict__ lepe,
               unsigned short* __restrict__ ohi)
{
    __shared__ unsigned short Ks[KT][44];     // 22 dw stride: 2-way max
    __shared__ unsigned short Vts[32][140];   // 70 dw stride: 2-way max

    const int tid  = threadIdx.x;
    const int lane = tid & 63;
    const int w    = tid >> 6;
    const int lo   = lane & 15;
    const int hi   = lane >> 4;

    const int bid = blockIdx.x;
    const int h   = bid & 7;         // XCD residue -> head
    const int j   = bid >> 3;        // 0..99
    const int qc  = j % 25;
    const int b   = j / 25;
    const int q0w = qc * 128 + w * 32;

    short8 qa[2];
    #pragma unroll
    for (int qg = 0; qg < 2; ++qg) {
        int row = min(q0w + qg * 16 + lo, SS - 1);
        qa[qg] = *(const short8*)(qb + ((size_t)(b * SS + row)) * CC + h * HD + hi * 8);
    }

    f32x4 oacc[2][2] = {};
    f32x4 dacc[2] = {};
    bf4 ones;
    ones[0] = (short)0x3F80; ones[1] = (short)0x3F80;
    ones[2] = (short)0x3F80; ones[3] = (short)0x3F80;

    const int krow = tid >> 2, kd0 = (tid & 3) * 8;    // K: 2 rows/thread
    const int vrow = tid >> 4, vk0 = (tid & 15) * 8;   // V: 2 rows/thread
    const unsigned short* kp0 = kb + ((size_t)b * SS + krow) * CC + h * HD + kd0;
    const unsigned short* vp0 = vt + ((size_t)((b * NH + h) * HD + vrow)) * SPAD + vk0;

    short8 kv0 = *(const short8*)(kp0);
    short8 kv1 = *(const short8*)(kp0 + (size_t)64 * CC);
    short8 vv0 = *(const short8*)(vp0);
    short8 vv1 = *(const short8*)(vp0 + (size_t)16 * SPAD);

    for (int k0 = 0; k0 < SPAD; k0 += KT) {
        __syncthreads();
        *(short8*)&Ks[krow][kd0]       = kv0;
        *(short8*)&Ks[64 + krow][kd0]  = kv1;
        *(short8*)&Vts[vrow][vk0]      = vv0;
        *(short8*)&Vts[16 + vrow][vk0] = vv1;
        __syncthreads();

        int kn = k0 + KT;
        if (kn < SPAD) {
            short8 z = {};
            kv0 = (kn + krow < SS)      ? *(const short8*)(kp0 + (size_t)kn * CC)        : z;
            kv1 = (kn + 64 + krow < SS) ? *(const short8*)(kp0 + (size_t)(kn + 64) * CC) : z;
            vv0 = *(const short8*)(vp0 + kn);
            vv1 = *(const short8*)(vp0 + (size_t)16 * SPAD + kn);
        }

        #pragma unroll
        for (int g = 0; g < 8; ++g) {
            short8 kf = *(const short8*)&Ks[g * 16 + lo][hi * 8];
            bf4 vf0 = *(const bf4*)&Vts[lo][g * 16 + hi * 4];
            bf4 vf1 = *(const bf4*)&Vts[16 + lo][g * 16 + hi * 4];
            #pragma unroll
            for (int qg = 0; qg < 2; ++qg) {
                f32x4 st = __builtin_amdgcn_mfma_f32_16x16x32_bf16(
                               kf, qa[qg], (f32x4){0.f, 0.f, 0.f, 0.f}, 0, 0, 0);
                float p0 = __builtin_amdgcn_exp2f(st[0]);
                float p1 = __builtin_amdgcn_exp2f(st[1]);
                float p2 = __builtin_amdgcn_exp2f(st[2]);
                float p3 = __builtin_amdgcn_exp2f(st[3]);
                unsigned u01 = __builtin_amdgcn_perm(
                    __float_as_uint(p1), __float_as_uint(p0), 0x07060302u);
                unsigned u23 = __builtin_amdgcn_perm(
                    __float_as_uint(p3), __float_as_uint(p2), 0x07060302u);
                union { unsigned u[2]; bf4 s; } pf;
                pf.u[0] = u01; pf.u[1] = u23;
                oacc[qg][0] = __builtin_amdgcn_mfma_f32_16x16x16bf16_1k(
                                  vf0, pf.s, oacc[qg][0], 0, 0, 0);
                oacc[qg][1] = __builtin_amdgcn_mfma_f32_16x16x16bf16_1k(
                                  vf1, pf.s, oacc[qg][1], 0, 0, 0);
                dacc[qg]    = __builtin_amdgcn_mfma_f32_16x16x16bf16_1k(
                                  ones, pf.s, dacc[qg], 0, 0, 0);
            }
        }
    }

    #pragma unroll
    for (int qg = 0; qg < 2; ++qg) {
        float inv = 1.f / (dacc[qg][0] - 63.f);   // remove 63 pad keys (p=1)
        int rowq = q0w + qg * 16 + lo;
        if (rowq < SS) {
            size_t base = ((size_t)(b * SS + rowq)) * CC + h * HD;
            #pragma unroll
            for (int dt = 0; dt < 2; ++dt) {
                bf4 lep = *(const bf4*)(lepe + base + dt * 16 + hi * 4);
                bf4 pk;
                #pragma unroll
                for (int r = 0; r < 4; ++r) {
                    float val = oacc[qg][dt][r] * inv + bf2f((unsigned short)lep[r]);
                    pk[r] = (short)f2bf(val);
                }
                *(bf4*)(ohi + base + dt * 16 + hi * 4) = pk;
            }
        }
    }
}

// ---------------------------------------------------------------------------
// Kernel 4: proj MFMA GEMM: out = ohi @ (Whi+Wlo)^T + b   (2-term split,
// W pre-split in `pre`), software-pipelined staging. Scatter to outputs.
// ---------------------------------------------------------------------------
__global__ __launch_bounds__(256)
void proj_mfma(const unsigned short* __restrict__ ohi,
               const unsigned short* __restrict__ pwhi,
               const unsigned short* __restrict__ pwlo,
               const float* __restrict__ bias, float* __restrict__ out)
{
    __shared__ unsigned short Ah[64][76];
    __shared__ unsigned short Wh[64][76];
    __shared__ unsigned short Wl[64][76];
    const int tid = threadIdx.x;
    const int w = tid >> 6, lane = tid & 63, lo = lane & 15, hi = lane >> 4;
    const int row0 = blockIdx.x * 64, col0 = blockIdx.y * 64;
    const int wm = (w & 1) * 32, wn = (w >> 1) * 32;

    f32x4 acc[2][2] = {};

    const int srow = tid >> 3, sc8 = (tid & 7) * 8;

    short8 ar[2], whr[2], wlr[2];
    #pragma unroll
    for (int i = 0; i < 2; ++i) {
        int gr = row0 + srow + i * 32;
        short8 ah = {};
        if (gr < M_ROWS) ah = *(const short8*)(ohi + (size_t)gr * CC + sc8);
        ar[i] = ah;
        int wr = col0 + srow + i * 32;
        whr[i] = *(const short8*)(pwhi + (size_t)wr * CC + sc8);
        wlr[i] = *(const short8*)(pwlo + (size_t)wr * CC + sc8);
    }

    for (int k0 = 0; k0 < CC; k0 += 64) {
        __syncthreads();
        #pragma unroll
        for (int i = 0; i < 2; ++i) {
            *(short8*)&Ah[srow + i * 32][sc8] = ar[i];
            *(short8*)&Wh[srow + i * 32][sc8] = whr[i];
            *(short8*)&Wl[srow + i * 32][sc8] = wlr[i];
        }
        __syncthreads();

        int kn = k0 + 64;
        if (kn < CC) {
            #pragma unroll
            for (int i = 0; i < 2; ++i) {
                int gr = row0 + srow + i * 32;
                short8 ah = {};
                if (gr < M_ROWS) ah = *(const short8*)(ohi + (size_t)gr * CC + kn + sc8);
                ar[i] = ah;
                int wr = col0 + srow + i * 32;
                whr[i] = *(const short8*)(pwhi + (size_t)wr * CC + kn + sc8);
                wlr[i] = *(const short8*)(pwlo + (size_t)wr * CC + kn + sc8);
            }
        }

        #pragma unroll
        for (int kk = 0; kk < 64; kk += 32) {
            short8 ah[2], wh[2], wl[2];
            #pragma unroll
            for (int m = 0; m < 2; ++m)
                ah[m] = *(const short8*)&Ah[wm + m * 16 + lo][kk + hi * 8];
            #pragma unroll
            for (int n = 0; n < 2; ++n) {
                wh[n] = *(const short8*)&Wh[wn + n * 16 + lo][kk + hi * 8];
                wl[n] = *(const short8*)&Wl[wn + n * 16 + lo][kk + hi * 8];
            }
            #pragma unroll
            for (int m = 0; m < 2; ++m)
                #pragma unroll
                for (int n = 0; n < 2; ++n) {
                    acc[m][n] = __builtin_amdgcn_mfma_f32_16x16x32_bf16(
                                    ah[m], wh[n], acc[m][n], 0, 0, 0);
                    acc[m][n] = __builtin_amdgcn_mfma_f32_16x16x32_bf16(
                                    ah[m], wl[n], acc[m][n], 0, 0, 0);
                }
        }
    }

    #pragma unroll
    for (int m = 0; m < 2; ++m) {
        #pragma unroll
        for (int rr = 0; rr < 4; ++rr) {
            int r = row0 + wm + m * 16 + hi * 4 + rr;
            if (r >= M_ROWS) continue;
            int b = r / SS, s = r % SS;
            #pragma unroll
            for (int n = 0; n < 2; ++n) {
                int col = col0 + wn + n * 16 + lo;
                float val = acc[m][n][rr] + bias[col];
                if (s == 0)
                    out[(size_t)BB * NN * CC + (size_t)b * CC + col] = val;
                else
                    out[((size_t)b * NN + (s - 1)) * CC + col] = val;
            }
        }
    }
}

extern "C" void kernel_launch(void* const* d_in, const int* in_sizes, int n_in,
                              void* d_out, int out_size, void* d_ws, size_t ws_size,
                              hipStream_t stream)
{
    const float* x      = (const float*)d_in[0];
    const float* cls    = (const float*)d_in[1];
    const float* qkv_w  = (const float*)d_in[2];
    const float* proj_w = (const float*)d_in[3];
    const float* proj_b = (const float*)d_in[4];
    const float* lepe_w = (const float*)d_in[5];
    const float* lepe_b = (const float*)d_in[6];
    float* out = (float*)d_out;

    // Workspace (ws ~256 MiB; we use ~39.4 MB)
    char* ws = (char*)d_ws;
    unsigned short* qb   = (unsigned short*)(ws + 0);          // 6,424,576
    unsigned short* kb   = (unsigned short*)(ws + 6424576);    // 6,424,576
    unsigned short* vt   = (unsigned short*)(ws + 12849152);   // 6,553,600
    unsigned short* xb   = (unsigned short*)(ws + 19402752);   // 6,424,576
    unsigned short* wb   = (unsigned short*)(ws + 25827328);   //   393,216
    unsigned short* lepe = (unsigned short*)(ws + 26220544);   // 6,424,576
    unsigned short* ohi  = (unsigned short*)(ws + 32645120);   // 6,424,576
    unsigned short* pwhi = (unsigned short*)(ws + 39069696);   //   131,072
    unsigned short* pwlo = (unsigned short*)(ws + 39200768);   //   131,072
    float*          wt   = (float*)(ws + 39331840);            //    25,600

    const int PRE_BLKS = 192 + 64 + 25 + 4;   // 285
    pre       <<<PRE_BLKS, 256, 0, stream>>>(cls, qkv_w, proj_w, lepe_w,
                                             xb, wb, pwhi, pwlo, wt, lepe);
    lepe_tiled<<<784, 256, 0, stream>>>(x, wt, lepe_b, lepe, xb);
    qkv_mfma  <<<dim3(200, 6), 256, 0, stream>>>(xb, wb, qb, kb, vt);
    attn_mfma <<<800, 256, 0, stream>>>(qb, kb, vt, lepe, ohi);
    proj_mfma <<<dim3(197, 4), 256, 0, stream>>>(ohi, pwhi, pwlo, proj_b, out);
}

// Round 14
// 193.428 us; speedup vs baseline: 1.1247x; 1.1247x over previous
//
#include <hip/hip_runtime.h>
#include <math.h>

#define BB 4
#define HH 56
#define WW 56
#define CC 256
#define NN 3136            // HH*WW
#define SS 3137            // 1 + NN
#define NH 8
#define HD 32
#define M_ROWS (BB * SS)   // 12548
#define SPAD 3200          // padded S for vt rows (63 pad keys)
#define QSCALE (0.17677669529663687f * 1.4426950408889634f)  // 1/sqrt(32) * log2(e)
#define KT 128             // attention key-tile

typedef short short8 __attribute__((ext_vector_type(8)));   // 8 bf16 (4 VGPRs)
typedef short bf4    __attribute__((ext_vector_type(4)));   // 4 bf16 (2 VGPRs)
typedef float f32x4  __attribute__((ext_vector_type(4)));   // MFMA C/D

static __device__ __forceinline__ unsigned short f2bf(float f) {
    union { float f; unsigned u; } a; a.f = f;
    unsigned r = a.u + 0x7FFF + ((a.u >> 16) & 1);   // RNE
    return (unsigned short)(r >> 16);
}
static __device__ __forceinline__ float bf2f(unsigned short h) {
    union { unsigned u; float f; } a; a.u = ((unsigned)h) << 16; return a.f;
}

// ---------------------------------------------------------------------------
// Kernel 0: pre — small elementwise prep (R12 configuration):
//   [0, 192)   wb = bf16(qkv_w), 4 rows/block
//   [+64)      pwhi/pwlo = bf16 split of proj_w
//   [+64)      vt pad cols [3136,3200) = 0
//   [+25)      wt[t][c] = lepe_w[c][t]  (transpose for coalesced staging)
//   [+4)       per-batch cls row: xb = bf16(cls), lepe = 0
// ---------------------------------------------------------------------------
__global__ __launch_bounds__(256)
void pre(const float* __restrict__ cls, const float* __restrict__ qkv_w,
         const float* __restrict__ proj_w, const float* __restrict__ lepe_w,
         unsigned short* __restrict__ xb, unsigned short* __restrict__ wb,
         unsigned short* __restrict__ pwhi, unsigned short* __restrict__ pwlo,
         unsigned short* __restrict__ vt, float* __restrict__ wt,
         unsigned short* __restrict__ lepe)
{
    const int B0 = 192;             // wb
    const int B1 = B0 + 64;         // pw
    const int B2 = B1 + 64;         // vt pad
    const int B3 = B2 + 25;         // wt transpose
    int blk = blockIdx.x, tid = threadIdx.x;
    if (blk < B0) {
        int row = blk * 4 + (tid >> 6);          // < 768
        int c0 = (tid & 63) * 4;
        float4 v = *(const float4*)(qkv_w + (size_t)row * CC + c0);
        bf4 pk;
        pk[0] = (short)f2bf(v.x); pk[1] = (short)f2bf(v.y);
        pk[2] = (short)f2bf(v.z); pk[3] = (short)f2bf(v.w);
        *(bf4*)(wb + (size_t)row * CC + c0) = pk;
    } else if (blk < B1) {
        int row = (blk - B0) * 4 + (tid >> 6);   // < 256
        int c0 = (tid & 63) * 4;
        float4 v = *(const float4*)(proj_w + (size_t)row * CC + c0);
        bf4 ph, pl;
        float vv[4] = {v.x, v.y, v.z, v.w};
        #pragma unroll
        for (int e = 0; e < 4; ++e) {
            unsigned short h = f2bf(vv[e]);
            ph[e] = (short)h;
            pl[e] = (short)f2bf(vv[e] - bf2f(h));
        }
        *(bf4*)(pwhi + (size_t)row * CC + c0) = ph;
        *(bf4*)(pwlo + (size_t)row * CC + c0) = pl;
    } else if (blk < B2) {
        int idx = blk - B1;                      // 0..63
        int row = idx * 16 + (tid >> 4);         // < 1024
        int col = 3136 + (tid & 15) * 4;
        bf4 z = {};
        *(bf4*)(vt + (size_t)row * SPAD + col) = z;
    } else if (blk < B3) {
        int t = blk - B2;                        // 0..24
        wt[(size_t)t * CC + tid] = lepe_w[(size_t)tid * 25 + t];
    } else {
        int b = blk - B3;                        // 0..3
        xb[((size_t)b * SS) * CC + tid] = f2bf(cls[(size_t)b * CC + tid]);
        lepe[((size_t)b * SS) * CC + tid] = 0;   // cls row: no conv term
    }
}

// ---------------------------------------------------------------------------
// Kernel 1: LDS-tiled LePE depthwise 5x5 conv + bias -> bf16 lepe, AND
// xb = bf16(x) emitted from the staged LDS tile.
// ---------------------------------------------------------------------------
__global__ __launch_bounds__(256)
void lepe_tiled(const float* __restrict__ x,
                const float* __restrict__ wt, const float* __restrict__ bias,
                unsigned short* __restrict__ lepe, unsigned short* __restrict__ xb)
{
    __shared__ unsigned short Xs[144][72];   // 12x12 halo x 64c (+8 pad)
    __shared__ float Wls[25][68];            // tap x 64c (+4 pad)

    const int tid = threadIdx.x;
    const int bid = blockIdx.x;
    const int sp  = bid % 49;
    const int ct  = (bid / 49) & 3;
    const int b   = bid / 196;
    const int y0 = (sp / 7) * 8, x0 = (sp % 7) * 8;
    const int c0 = ct * 64;

    const int cq = tid & 15;                 // c-quad within 64
    const int pg = tid >> 4;                 // 0..15

    #pragma unroll
    for (int r = 0; r < 9; ++r) {
        int seg = r * 16 + pg;               // 0..143
        int dy = seg / 12, dx = seg % 12;
        int yy = y0 + dy - 2, xc = x0 + dx - 2;
        bf4 v = {};
        if (yy >= 0 && yy < HH && xc >= 0 && xc < WW) {
            float4 f = *(const float4*)(x + (((size_t)b * HH + yy) * WW + xc) * CC
                                        + c0 + cq * 4);
            v[0] = (short)f2bf(f.x); v[1] = (short)f2bf(f.y);
            v[2] = (short)f2bf(f.z); v[3] = (short)f2bf(f.w);
        }
        *(bf4*)&Xs[seg][cq * 4] = v;
    }
    for (int idx = tid; idx < 1600; idx += 256) {
        int t = idx >> 6, c = idx & 63;
        Wls[t][c] = wt[(size_t)t * CC + c0 + c];
    }
    __syncthreads();

    float4 bq = *(const float4*)(bias + c0 + cq * 4);
    f32x4 acc[4];
    #pragma unroll
    for (int it = 0; it < 4; ++it) {
        acc[it][0] = bq.x; acc[it][1] = bq.y; acc[it][2] = bq.z; acc[it][3] = bq.w;
    }
    int hbase[4];
    #pragma unroll
    for (int it = 0; it < 4; ++it) {
        int pos = it * 16 + pg;              // 0..63
        hbase[it] = (pos >> 3) * 12 + (pos & 7);
    }

    // emit xb for this tile's 64 interior positions
    #pragma unroll
    for (int it = 0; it < 4; ++it) {
        int pos = it * 16 + pg;
        int py = pos >> 3, px = pos & 7;
        uint2 dv = *(const uint2*)&Xs[(py + 2) * 12 + (px + 2)][cq * 4];
        *(uint2*)(xb + ((size_t)(b * SS + 1 + (y0 + py) * WW + (x0 + px))) * CC
                  + c0 + cq * 4) = dv;
    }

    #pragma unroll
    for (int t = 0; t < 25; ++t) {
        int dy = t / 5, dx = t % 5;
        float4 wq = *(const float4*)&Wls[t][cq * 4];
        #pragma unroll
        for (int it = 0; it < 4; ++it) {
            const unsigned short* xp = &Xs[hbase[it] + dy * 12 + dx][cq * 4];
            uint2 dv = *(const uint2*)xp;    // 4 bf16, ds_read_b64
            float e0 = __uint_as_float(dv.x << 16);
            float e1 = __uint_as_float(dv.x & 0xFFFF0000u);
            float e2 = __uint_as_float(dv.y << 16);
            float e3 = __uint_as_float(dv.y & 0xFFFF0000u);
            acc[it][0] += e0 * wq.x; acc[it][1] += e1 * wq.y;
            acc[it][2] += e2 * wq.z; acc[it][3] += e3 * wq.w;
        }
    }

    #pragma unroll
    for (int it = 0; it < 4; ++it) {
        int pos = it * 16 + pg;
        int py = pos >> 3, px = pos & 7;
        bf4 pk;
        pk[0] = (short)f2bf(acc[it][0]); pk[1] = (short)f2bf(acc[it][1]);
        pk[2] = (short)f2bf(acc[it][2]); pk[3] = (short)f2bf(acc[it][3]);
        *(bf4*)(lepe + ((size_t)(b * SS + 1 + (y0 + py) * WW + (x0 + px))) * CC
                + c0 + cq * 4) = pk;
    }
}

// ---------------------------------------------------------------------------
// Kernel 2: qkv bf16 MFMA GEMM: [12548x256] @ [768x256]^T  (R12 epilogue:
// direct scattered bf4 vt stores — R13's LDS-transpose epilogue regressed
// 23 us: vt is L2-resident, sector amplification didn't cost wall time but
// the extra barriers/LDS round-trip did).
// ---------------------------------------------------------------------------
__global__ __launch_bounds__(256)
void qkv_mfma(const unsigned short* __restrict__ xb,
              const unsigned short* __restrict__ wb,
              unsigned short* __restrict__ qb, unsigned short* __restrict__ kb,
              unsigned short* __restrict__ vt)
{
    __shared__ unsigned short As[64][76];
    __shared__ unsigned short Bs[128][76];
    const int tid = threadIdx.x;
    const int w = tid >> 6, lane = tid & 63, lo = lane & 15, hi = lane >> 4;
    const int b0 = blockIdx.x / 50;
    const int s0blk = (blockIdx.x % 50) * 64;
    const int col0 = blockIdx.y * 128;
    const int wm = (w & 1) * 32, wn = (w >> 1) * 64;

    f32x4 acc[2][4] = {};

    const int arow = tid >> 3, ac8 = (tid & 7) * 8;
    const int brow = tid >> 3, bc8 = (tid & 7) * 8;

    short8 avr[2], bvr[4];
    #pragma unroll
    for (int i = 0; i < 2; ++i) {
        int row = arow + i * 32;
        short8 av = {};
        if (s0blk + row < SS)
            av = *(const short8*)(xb + (size_t)(b0 * SS + s0blk + row) * CC + ac8);
        avr[i] = av;
    }
    #pragma unroll
    for (int i = 0; i < 4; ++i)
        bvr[i] = *(const short8*)(wb + (size_t)(col0 + brow + i * 32) * CC + bc8);

    for (int k0 = 0; k0 < CC; k0 += 64) {
        __syncthreads();
        #pragma unroll
        for (int i = 0; i < 2; ++i)
            *(short8*)&As[arow + i * 32][ac8] = avr[i];
        #pragma unroll
        for (int i = 0; i < 4; ++i)
            *(short8*)&Bs[brow + i * 32][bc8] = bvr[i];
        __syncthreads();

        int kn = k0 + 64;
        if (kn < CC) {
            #pragma unroll
            for (int i = 0; i < 2; ++i) {
                int row = arow + i * 32;
                short8 av = {};
                if (s0blk + row < SS)
                    av = *(const short8*)(xb + (size_t)(b0 * SS + s0blk + row) * CC + kn + ac8);
                avr[i] = av;
            }
            #pragma unroll
            for (int i = 0; i < 4; ++i)
                bvr[i] = *(const short8*)(wb + (size_t)(col0 + brow + i * 32) * CC + kn + bc8);
        }

        #pragma unroll
        for (int kk = 0; kk < 64; kk += 32) {
            short8 af[2], bf_[4];
            #pragma unroll
            for (int m = 0; m < 2; ++m)
                af[m] = *(const short8*)&As[wm + m * 16 + lo][kk + hi * 8];
            #pragma unroll
            for (int n = 0; n < 4; ++n)
                bf_[n] = *(const short8*)&Bs[wn + n * 16 + lo][kk + hi * 8];
            #pragma unroll
            for (int m = 0; m < 2; ++m)
                #pragma unroll
                for (int n = 0; n < 4; ++n)
                    acc[m][n] = __builtin_amdgcn_mfma_f32_16x16x32_bf16(
                                    af[m], bf_[n], acc[m][n], 0, 0, 0);
        }
    }

    const int part = col0 >> 8;   // 0=q, 1=k, 2=v (block-uniform)
    if (part < 2) {
        #pragma unroll
        for (int m = 0; m < 2; ++m) {
            #pragma unroll
            for (int rr = 0; rr < 4; ++rr) {
                int s = s0blk + wm + m * 16 + hi * 4 + rr;
                if (s >= SS) continue;
                size_t r = (size_t)(b0 * SS + s);
                #pragma unroll
                for (int n = 0; n < 4; ++n) {
                    int cc = (col0 + wn + n * 16 + lo) & 255;
                    float val = acc[m][n][rr];
                    if (part == 0) qb[r * CC + cc] = f2bf(val * QSCALE);
                    else           kb[r * CC + cc] = f2bf(val);
                }
            }
        }
    } else {
        #pragma unroll
        for (int m = 0; m < 2; ++m) {
            int s0 = s0blk + wm + m * 16 + hi * 4;   // multiple of 4
            if (s0 >= SS) continue;
            bool fast = (s0 + 3 < SS);
            #pragma unroll
            for (int n = 0; n < 4; ++n) {
                int cc = (col0 + wn + n * 16 + lo) & 255;
                int hh = cc >> 5, d = cc & 31;
                unsigned short* vrow = vt + (size_t)((b0 * NH + hh) * HD + d) * SPAD;
                if (fast) {
                    bf4 pk;
                    pk[0] = (short)f2bf(acc[m][n][0]);
                    pk[1] = (short)f2bf(acc[m][n][1]);
                    pk[2] = (short)f2bf(acc[m][n][2]);
                    pk[3] = (short)f2bf(acc[m][n][3]);
                    *(bf4*)(vrow + s0) = pk;
                } else {
                    for (int rr = 0; rr < 4 && s0 + rr < SS; ++rr)
                        vrow[s0 + rr] = f2bf(acc[m][n][rr]);
                }
            }
        }
    }
}

// ---------------------------------------------------------------------------
// Kernel 3: bf16 MFMA flash attention, transposed-S, ones-MFMA denominator,
// software-pipelined staging, 32 q/wave. UNCHANGED (structurally pinned:
// occupancy/LDS-traffic/conflict levers all measured neutral at 91-93 us).
// ---------------------------------------------------------------------------
__global__ __launch_bounds__(256)
void attn_mfma(const unsigned short* __restrict__ qb,
               const unsigned short* __restrict__ kb,
               const unsigned short* __restrict__ vt,
               const unsigned short* __restrict__ lepe,
               unsigned short* __restrict__ ohi)
{
    __shared__ unsigned short Ks[KT][44];     // 22 dw stride: 2-way max
    __shared__ unsigned short Vts[32][140];   // 70 dw stride: 2-way max

    const int tid  = threadIdx.x;
    const int lane = tid & 63;
    const int w    = tid >> 6;
    const int lo   = lane & 15;
    const int hi   = lane >> 4;

    const int bid = blockIdx.x;
    const int h   = bid & 7;         // XCD residue -> head
    const int j   = bid >> 3;        // 0..99
    const int qc  = j % 25;
    const int b   = j / 25;
    const int q0w = qc * 128 + w * 32;

    short8 qa[2];
    #pragma unroll
    for (int qg = 0; qg < 2; ++qg) {
        int row = min(q0w + qg * 16 + lo, SS - 1);
        qa[qg] = *(const short8*)(qb + ((size_t)(b * SS + row)) * CC + h * HD + hi * 8);
    }

    f32x4 oacc[2][2] = {};
    f32x4 dacc[2] = {};
    bf4 ones;
    ones[0] = (short)0x3F80; ones[1] = (short)0x3F80;
    ones[2] = (short)0x3F80; ones[3] = (short)0x3F80;

    const int krow = tid >> 2, kd0 = (tid & 3) * 8;    // K: 2 rows/thread
    const int vrow = tid >> 4, vk0 = (tid & 15) * 8;   // V: 2 rows/thread
    const unsigned short* kp0 = kb + ((size_t)b * SS + krow) * CC + h * HD + kd0;
    const unsigned short* vp0 = vt + ((size_t)((b * NH + h) * HD + vrow)) * SPAD + vk0;

    short8 kv0 = *(const short8*)(kp0);
    short8 kv1 = *(const short8*)(kp0 + (size_t)64 * CC);
    short8 vv0 = *(const short8*)(vp0);
    short8 vv1 = *(const short8*)(vp0 + (size_t)16 * SPAD);

    for (int k0 = 0; k0 < SPAD; k0 += KT) {
        __syncthreads();
        *(short8*)&Ks[krow][kd0]       = kv0;
        *(short8*)&Ks[64 + krow][kd0]  = kv1;
        *(short8*)&Vts[vrow][vk0]      = vv0;
        *(short8*)&Vts[16 + vrow][vk0] = vv1;
        __syncthreads();

        int kn = k0 + KT;
        if (kn < SPAD) {
            short8 z = {};
            kv0 = (kn + krow < SS)      ? *(const short8*)(kp0 + (size_t)kn * CC)        : z;
            kv1 = (kn + 64 + krow < SS) ? *(const short8*)(kp0 + (size_t)(kn + 64) * CC) : z;
            vv0 = *(const short8*)(vp0 + kn);
            vv1 = *(const short8*)(vp0 + (size_t)16 * SPAD + kn);
        }

        #pragma unroll
        for (int g = 0; g < 8; ++g) {
            short8 kf = *(const short8*)&Ks[g * 16 + lo][hi * 8];
            bf4 vf0 = *(const bf4*)&Vts[lo][g * 16 + hi * 4];
            bf4 vf1 = *(const bf4*)&Vts[16 + lo][g * 16 + hi * 4];
            #pragma unroll
            for (int qg = 0; qg < 2; ++qg) {
                f32x4 st = __builtin_amdgcn_mfma_f32_16x16x32_bf16(
                               kf, qa[qg], (f32x4){0.f, 0.f, 0.f, 0.f}, 0, 0, 0);
                float p0 = __builtin_amdgcn_exp2f(st[0]);
                float p1 = __builtin_amdgcn_exp2f(st[1]);
                float p2 = __builtin_amdgcn_exp2f(st[2]);
                float p3 = __builtin_amdgcn_exp2f(st[3]);
                unsigned u01 = __builtin_amdgcn_perm(
                    __float_as_uint(p1), __float_as_uint(p0), 0x07060302u);
                unsigned u23 = __builtin_amdgcn_perm(
                    __float_as_uint(p3), __float_as_uint(p2), 0x07060302u);
                union { unsigned u[2]; bf4 s; } pf;
                pf.u[0] = u01; pf.u[1] = u23;
                oacc[qg][0] = __builtin_amdgcn_mfma_f32_16x16x16bf16_1k(
                                  vf0, pf.s, oacc[qg][0], 0, 0, 0);
                oacc[qg][1] = __builtin_amdgcn_mfma_f32_16x16x16bf16_1k(
                                  vf1, pf.s, oacc[qg][1], 0, 0, 0);
                dacc[qg]    = __builtin_amdgcn_mfma_f32_16x16x16bf16_1k(
                                  ones, pf.s, dacc[qg], 0, 0, 0);
            }
        }
    }

    #pragma unroll
    for (int qg = 0; qg < 2; ++qg) {
        float inv = 1.f / (dacc[qg][0] - 63.f);   // remove 63 pad keys (p=1)
        int rowq = q0w + qg * 16 + lo;
        if (rowq < SS) {
            size_t base = ((size_t)(b * SS + rowq)) * CC + h * HD;
            #pragma unroll
            for (int dt = 0; dt < 2; ++dt) {
                bf4 lep = *(const bf4*)(lepe + base + dt * 16 + hi * 4);
                bf4 pk;
                #pragma unroll
                for (int r = 0; r < 4; ++r) {
                    float val = oacc[qg][dt][r] * inv + bf2f((unsigned short)lep[r]);
                    pk[r] = (short)f2bf(val);
                }
                *(bf4*)(ohi + base + dt * 16 + hi * 4) = pk;
            }
        }
    }
}

// ---------------------------------------------------------------------------
// Kernel 4: proj MFMA GEMM: out = ohi @ (Whi+Wlo)^T + b   (2-term split,
// W pre-split in `pre`), software-pipelined staging. Scatter to outputs.
// ---------------------------------------------------------------------------
__global__ __launch_bounds__(256)
void proj_mfma(const unsigned short* __restrict__ ohi,
               const unsigned short* __restrict__ pwhi,
               const unsigned short* __restrict__ pwlo,
               const float* __restrict__ bias, float* __restrict__ out)
{
    __shared__ unsigned short Ah[64][76];
    __shared__ unsigned short Wh[64][76];
    __shared__ unsigned short Wl[64][76];
    const int tid = threadIdx.x;
    const int w = tid >> 6, lane = tid & 63, lo = lane & 15, hi = lane >> 4;
    const int row0 = blockIdx.x * 64, col0 = blockIdx.y * 64;
    const int wm = (w & 1) * 32, wn = (w >> 1) * 32;

    f32x4 acc[2][2] = {};

    const int srow = tid >> 3, sc8 = (tid & 7) * 8;

    short8 ar[2], whr[2], wlr[2];
    #pragma unroll
    for (int i = 0; i < 2; ++i) {
        int gr = row0 + srow + i * 32;
        short8 ah = {};
        if (gr < M_ROWS) ah = *(const short8*)(ohi + (size_t)gr * CC + sc8);
        ar[i] = ah;
        int wr = col0 + srow + i * 32;
        whr[i] = *(const short8*)(pwhi + (size_t)wr * CC + sc8);
        wlr[i] = *(const short8*)(pwlo + (size_t)wr * CC + sc8);
    }

    for (int k0 = 0; k0 < CC; k0 += 64) {
        __syncthreads();
        #pragma unroll
        for (int i = 0; i < 2; ++i) {
            *(short8*)&Ah[srow + i * 32][sc8] = ar[i];
            *(short8*)&Wh[srow + i * 32][sc8] = whr[i];
            *(short8*)&Wl[srow + i * 32][sc8] = wlr[i];
        }
        __syncthreads();

        int kn = k0 + 64;
        if (kn < CC) {
            #pragma unroll
            for (int i = 0; i < 2; ++i) {
                int gr = row0 + srow + i * 32;
                short8 ah = {};
                if (gr < M_ROWS) ah = *(const short8*)(ohi + (size_t)gr * CC + kn + sc8);
                ar[i] = ah;
                int wr = col0 + srow + i * 32;
                whr[i] = *(const short8*)(pwhi + (size_t)wr * CC + kn + sc8);
                wlr[i] = *(const short8*)(pwlo + (size_t)wr * CC + kn + sc8);
            }
        }

        #pragma unroll
        for (int kk = 0; kk < 64; kk += 32) {
            short8 ah[2], wh[2], wl[2];
            #pragma unroll
            for (int m = 0; m < 2; ++m)
                ah[m] = *(const short8*)&Ah[wm + m * 16 + lo][kk + hi * 8];
            #pragma unroll
            for (int n = 0; n < 2; ++n) {
                wh[n] = *(const short8*)&Wh[wn + n * 16 + lo][kk + hi * 8];
                wl[n] = *(const short8*)&Wl[wn + n * 16 + lo][kk + hi * 8];
            }
            #pragma unroll
            for (int m = 0; m < 2; ++m)
                #pragma unroll
                for (int n = 0; n < 2; ++n) {
                    acc[m][n] = __builtin_amdgcn_mfma_f32_16x16x32_bf16(
                                    ah[m], wh[n], acc[m][n], 0, 0, 0);
                    acc[m][n] = __builtin_amdgcn_mfma_f32_16x16x32_bf16(
                                    ah[m], wl[n], acc[m][n], 0, 0, 0);
                }
        }
    }

    #pragma unroll
    for (int m = 0; m < 2; ++m) {
        #pragma unroll
        for (int rr = 0; rr < 4; ++rr) {
            int r = row0 + wm + m * 16 + hi * 4 + rr;
            if (r >= M_ROWS) continue;
            int b = r / SS, s = r % SS;
            #pragma unroll
            for (int n = 0; n < 2; ++n) {
                int col = col0 + wn + n * 16 + lo;
                float val = acc[m][n][rr] + bias[col];
                if (s == 0)
                    out[(size_t)BB * NN * CC + (size_t)b * CC + col] = val;
                else
                    out[((size_t)b * NN + (s - 1)) * CC + col] = val;
            }
        }
    }
}

extern "C" void kernel_launch(void* const* d_in, const int* in_sizes, int n_in,
                              void* d_out, int out_size, void* d_ws, size_t ws_size,
                              hipStream_t stream)
{
    const float* x      = (const float*)d_in[0];
    const float* cls    = (const float*)d_in[1];
    const float* qkv_w  = (const float*)d_in[2];
    const float* proj_w = (const float*)d_in[3];
    const float* proj_b = (const float*)d_in[4];
    const float* lepe_w = (const float*)d_in[5];
    const float* lepe_b = (const float*)d_in[6];
    float* out = (float*)d_out;

    // Workspace (ws ~256 MiB; we use ~39.4 MB)
    char* ws = (char*)d_ws;
    unsigned short* qb   = (unsigned short*)(ws + 0);          // 6,424,576
    unsigned short* kb   = (unsigned short*)(ws + 6424576);    // 6,424,576
    unsigned short* vt   = (unsigned short*)(ws + 12849152);   // 6,553,600
    unsigned short* xb   = (unsigned short*)(ws + 19402752);   // 6,424,576
    unsigned short* wb   = (unsigned short*)(ws + 25827328);   //   393,216
    unsigned short* lepe = (unsigned short*)(ws + 26220544);   // 6,424,576
    unsigned short* ohi  = (unsigned short*)(ws + 32645120);   // 6,424,576
    unsigned short* pwhi = (unsigned short*)(ws + 39069696);   //   131,072
    unsigned short* pwlo = (unsigned short*)(ws + 39200768);   //   131,072
    float*          wt   = (float*)(ws + 39331840);            //    25,600

    const int PRE_BLKS = 192 + 64 + 64 + 25 + 4;   // 349
    pre       <<<PRE_BLKS, 256, 0, stream>>>(cls, qkv_w, proj_w, lepe_w,
                                             xb, wb, pwhi, pwlo, vt, wt, lepe);
    lepe_tiled<<<784, 256, 0, stream>>>(x, wt, lepe_b, lepe, xb);
    qkv_mfma  <<<dim3(200, 6), 256, 0, stream>>>(xb, wb, qb, kb, vt);
    attn_mfma <<<800, 256, 0, stream>>>(qb, kb, vt, lepe, ohi);
    proj_mfma <<<dim3(197, 4), 256, 0, stream>>>(ohi, pwhi, pwlo, proj_b, out);
}